// Round 2
// baseline (555.694 us; speedup 1.0000x reference)
//
#include <hip/hip_runtime.h>
#include <hip/hip_bf16.h>

#define VOUT 50257
#define KHOT 1024
#define DIM  1024
#define RHOT 384
#define RCOLD 32
#define RF   416   // RHOT + RCOLD

typedef __attribute__((ext_vector_type(8))) short short8;
typedef __attribute__((ext_vector_type(4))) float f32x4;

// ---------------- K0: convert f32 weights to bf16 ----------------
__global__ void k_convert(const float* __restrict__ Bh, const float* __restrict__ Bc,
                          const float* __restrict__ Uh, const float* __restrict__ Uc,
                          __hip_bfloat16* __restrict__ Bmat,
                          __hip_bfloat16* __restrict__ UhB,
                          __hip_bfloat16* __restrict__ UcB) {
  const int nBh = RHOT * DIM;            // 393216
  const int nBm = RF * DIM;              // 425984
  const int nUh = KHOT * RHOT;           // 393216
  const int nUc = (VOUT - KHOT) * RCOLD; // 1575456
  const int total = nBm + nUh + nUc;
  for (int i = blockIdx.x * blockDim.x + threadIdx.x; i < total;
       i += gridDim.x * blockDim.x) {
    if (i < nBm) {
      float v = (i < nBh) ? Bh[i] : Bc[i - nBh];
      Bmat[i] = __float2bfloat16(v);
    } else if (i < nBm + nUh) {
      UhB[i - nBm] = __float2bfloat16(Uh[i - nBm]);
    } else {
      int j = i - nBm - nUh;
      UcB[j] = __float2bfloat16(Uc[j]);
    }
  }
}

// ---------------- K1: G = Bmat @ Bmat^T  (416x416, K=1024), f32 out ----------------
__global__ __launch_bounds__(256) void k_gram(const __hip_bfloat16* __restrict__ Bmat,
                                              float* __restrict__ G) {
  const int wave = threadIdx.x >> 6;
  const int lane = threadIdx.x & 63;
  const int idx = blockIdx.x * 4 + wave;
  if (idx >= 26 * 26) return;  // wave-uniform
  const int ti = idx / 26, tj = idx % 26;
  const int i0 = ti * 16, j0 = tj * 16;
  const int col16 = lane & 15;
  const int g4 = lane >> 4;

  f32x4 acc = (f32x4){0.f, 0.f, 0.f, 0.f};
  const __hip_bfloat16* arow = Bmat + (size_t)(i0 + col16) * DIM;
  const __hip_bfloat16* brow = Bmat + (size_t)(j0 + col16) * DIM;
#pragma unroll 4
  for (int ks = 0; ks < DIM / 32; ++ks) {
    short8 a = *reinterpret_cast<const short8*>(arow + ks * 32 + g4 * 8);
    short8 b = *reinterpret_cast<const short8*>(brow + ks * 32 + g4 * 8);
    acc = __builtin_amdgcn_mfma_f32_16x16x32_bf16(a, b, acc, 0, 0, 0);
  }
#pragma unroll
  for (int r = 0; r < 4; ++r)
    G[(size_t)(i0 + g4 * 4 + r) * RF + j0 + col16] = acc[r];
}

// ---------------- K2: per-token F[n] = u @ G  (f32 math, bf16 out) ----------------
__global__ void k_encode(const int* __restrict__ tokens, const int* __restrict__ o2n,
                         const float* __restrict__ Uh, const float* __restrict__ Uc,
                         const float* __restrict__ G, __hip_bfloat16* __restrict__ F) {
  const int n = blockIdx.x;
  __shared__ float u[RHOT];
  const int tok = tokens[n];
  const int tn = o2n[tok];
  const bool hot = tn < KHOT;
  const int R = hot ? RHOT : RCOLD;
  const float* urow = hot ? (Uh + (size_t)tn * RHOT) : (Uc + (size_t)(tn - KHOT) * RCOLD);
  for (int r = threadIdx.x; r < R; r += blockDim.x) u[r] = urow[r];
  __syncthreads();
  const int gbase = hot ? 0 : RHOT;
  for (int c = threadIdx.x; c < RF; c += blockDim.x) {
    float acc = 0.f;
    for (int r = 0; r < R; ++r) acc += u[r] * G[(size_t)(gbase + r) * RF + c];
    F[(size_t)n * RF + c] = __float2bfloat16(acc);
  }
}

// ---------------- K3 v2: fused logits, block tile = 1024 cols x 64 rows ----------------
// grid (50, 64); 4 waves; per subtile s (0..15), wave w covers cols bx*1024 + s*64 + w*16.
// Cold F slice staged once in LDS (pitch 40 -> only 2-way bank alias, free).
// Each output row receives a sequential 4KB run from one block -> DRAM-friendly writes.
#define CPB 1024
#define RPB 64
#define NSUB (CPB / 64)

__global__ __launch_bounds__(256) void k_out(const int* __restrict__ o2n,
                                             const __hip_bfloat16* __restrict__ F,
                                             const __hip_bfloat16* __restrict__ Uh,
                                             const __hip_bfloat16* __restrict__ Uc,
                                             const float* __restrict__ log_alpha,
                                             const float* __restrict__ bias,
                                             float* __restrict__ out) {
  __shared__ __hip_bfloat16 Fc[RPB][40];  // cold slice [64 rows][32 cols], pitch 40
  const int tid = threadIdx.x;
  const int wave = tid >> 6;
  const int lane = tid & 63;
  const int col16 = lane & 15;
  const int g4 = lane >> 4;
  const int n0 = blockIdx.y * RPB;
  const int cbase = blockIdx.x * CPB;
  const float alpha = expf(log_alpha[0]);
  const short8 zero8 = (short8){0, 0, 0, 0, 0, 0, 0, 0};

  // stage cold F slice: 64 rows x 32 cols (16B per thread, 256 threads exactly)
  {
    const int row = tid >> 2, chunk = tid & 3;
    short8 v = *reinterpret_cast<const short8*>(F + (size_t)(n0 + row) * RF + RHOT + chunk * 8);
    *reinterpret_cast<short8*>(&Fc[row][chunk * 8]) = v;
  }
  __syncthreads();

  for (int s = 0; s < NSUB; ++s) {
    const int v = cbase + s * 64 + wave * 16 + col16;
    const int vc = (v < VOUT) ? v : (VOUT - 1);
    const int src = o2n[vc];
    const bool ishot = src < KHOT;
    const float bv = bias[vc];

    f32x4 acc[4];
#pragma unroll
    for (int t = 0; t < 4; ++t) acc[t] = (f32x4){0.f, 0.f, 0.f, 0.f};

    // cold contribution: K = 32 from LDS
    if (__any(!ishot)) {
      short8 bfrag = zero8;
      if (!ishot)
        bfrag = *reinterpret_cast<const short8*>(Uc + (size_t)(src - KHOT) * RCOLD + g4 * 8);
#pragma unroll
      for (int t = 0; t < 4; ++t) {
        short8 afrag = *reinterpret_cast<const short8*>(&Fc[t * 16 + col16][g4 * 8]);
        acc[t] = __builtin_amdgcn_mfma_f32_16x16x32_bf16(afrag, bfrag, acc[t], 0, 0, 0);
      }
    }
    // hot contribution: K = 384, direct from global (rare columns)
    if (__any(ishot)) {
      for (int ks = 0; ks < RHOT / 32; ++ks) {
        short8 bfrag = zero8;
        if (ishot)
          bfrag = *reinterpret_cast<const short8*>(Uh + (size_t)src * RHOT + ks * 32 + g4 * 8);
#pragma unroll
        for (int t = 0; t < 4; ++t) {
          short8 afrag = *reinterpret_cast<const short8*>(
              F + (size_t)(n0 + t * 16 + col16) * RF + ks * 32 + g4 * 8);
          acc[t] = __builtin_amdgcn_mfma_f32_16x16x32_bf16(afrag, bfrag, acc[t], 0, 0, 0);
        }
      }
    }
    // epilogue: scale + bias + store
    if (v < VOUT) {
#pragma unroll
      for (int t = 0; t < 4; ++t) {
#pragma unroll
        for (int r = 0; r < 4; ++r) {
          int n = n0 + t * 16 + g4 * 4 + r;
          out[(size_t)n * VOUT + v] = acc[t][r] * alpha + bv;
        }
      }
    }
  }
}

extern "C" void kernel_launch(void* const* d_in, const int* in_sizes, int n_in,
                              void* d_out, int out_size, void* d_ws, size_t ws_size,
                              hipStream_t stream) {
  const int* tokens    = (const int*)d_in[0];
  const int* o2n       = (const int*)d_in[1];
  const float* B_hot   = (const float*)d_in[2];
  const float* B_cold  = (const float*)d_in[3];
  const float* U_hot   = (const float*)d_in[4];
  const float* U_cold  = (const float*)d_in[5];
  const float* log_a   = (const float*)d_in[6];
  const float* bias    = (const float*)d_in[7];
  float* out = (float*)d_out;

  const int N = in_sizes[0];  // 4096 tokens

  // workspace layout (bytes)
  char* ws = (char*)d_ws;
  __hip_bfloat16* Bmat = (__hip_bfloat16*)(ws + 0);             // 425984*2
  __hip_bfloat16* UhB  = (__hip_bfloat16*)(ws + (1u << 20));    // 393216*2
  __hip_bfloat16* UcB  = (__hip_bfloat16*)(ws + (2u << 20));    // 1575456*2
  float*          G    = (float*)(ws + (6u << 20));             // 416*416*4
  __hip_bfloat16* F    = (__hip_bfloat16*)(ws + (7u << 20));    // 4096*416*2

  k_convert<<<2048, 256, 0, stream>>>(B_hot, B_cold, U_hot, U_cold, Bmat, UhB, UcB);
  k_gram<<<169, 256, 0, stream>>>(Bmat, G);
  k_encode<<<N, 256, 0, stream>>>(tokens, o2n, U_hot, U_cold, G, F);

  dim3 grid((VOUT + CPB - 1) / CPB, N / RPB);
  k_out<<<grid, 256, 0, stream>>>(o2n, F, UhB, UcB, log_a, bias, out);
}

// Round 3
// 322.549 us; speedup vs baseline: 1.7228x; 1.7228x over previous
//
#include <hip/hip_runtime.h>
#include <hip/hip_bf16.h>

#define VOUT 50257
#define KHOT 1024
#define DIM  1024
#define RHOT 384
#define RCOLD 32
#define RF   416   // RHOT + RCOLD

typedef __attribute__((ext_vector_type(8))) short short8;
typedef __attribute__((ext_vector_type(4))) float f32x4;

// ---------------- K0: convert f32 weights to bf16 ----------------
__global__ void k_convert(const float* __restrict__ Bh, const float* __restrict__ Bc,
                          const float* __restrict__ Uh, const float* __restrict__ Uc,
                          __hip_bfloat16* __restrict__ Bmat,
                          __hip_bfloat16* __restrict__ UhB,
                          __hip_bfloat16* __restrict__ UcB) {
  const int nBh = RHOT * DIM;            // 393216
  const int nBm = RF * DIM;              // 425984
  const int nUh = KHOT * RHOT;           // 393216
  const int nUc = (VOUT - KHOT) * RCOLD; // 1575456
  const int total = nBm + nUh + nUc;
  for (int i = blockIdx.x * blockDim.x + threadIdx.x; i < total;
       i += gridDim.x * blockDim.x) {
    if (i < nBm) {
      float v = (i < nBh) ? Bh[i] : Bc[i - nBh];
      Bmat[i] = __float2bfloat16(v);
    } else if (i < nBm + nUh) {
      UhB[i - nBm] = __float2bfloat16(Uh[i - nBm]);
    } else {
      int j = i - nBm - nUh;
      UcB[j] = __float2bfloat16(Uc[j]);
    }
  }
}

// ---------------- K1: G = Bmat @ Bmat^T  (416x416, K=1024), f32 out ----------------
__global__ __launch_bounds__(256) void k_gram(const __hip_bfloat16* __restrict__ Bmat,
                                              float* __restrict__ G) {
  const int wave = threadIdx.x >> 6;
  const int lane = threadIdx.x & 63;
  const int idx = blockIdx.x * 4 + wave;
  if (idx >= 26 * 26) return;  // wave-uniform
  const int ti = idx / 26, tj = idx % 26;
  const int i0 = ti * 16, j0 = tj * 16;
  const int col16 = lane & 15;
  const int g4 = lane >> 4;

  f32x4 acc = (f32x4){0.f, 0.f, 0.f, 0.f};
  const __hip_bfloat16* arow = Bmat + (size_t)(i0 + col16) * DIM;
  const __hip_bfloat16* brow = Bmat + (size_t)(j0 + col16) * DIM;
#pragma unroll 4
  for (int ks = 0; ks < DIM / 32; ++ks) {
    short8 a = *reinterpret_cast<const short8*>(arow + ks * 32 + g4 * 8);
    short8 b = *reinterpret_cast<const short8*>(brow + ks * 32 + g4 * 8);
    acc = __builtin_amdgcn_mfma_f32_16x16x32_bf16(a, b, acc, 0, 0, 0);
  }
#pragma unroll
  for (int r = 0; r < 4; ++r)
    G[(size_t)(i0 + g4 * 4 + r) * RF + j0 + col16] = acc[r];
}

// ---------------- K2: per-token F[n] = u @ G  (f32 math, bf16 out) ----------------
__global__ void k_encode(const int* __restrict__ tokens, const int* __restrict__ o2n,
                         const float* __restrict__ Uh, const float* __restrict__ Uc,
                         const float* __restrict__ G, __hip_bfloat16* __restrict__ F) {
  const int n = blockIdx.x;
  __shared__ float u[RHOT];
  const int tok = tokens[n];
  const int tn = o2n[tok];
  const bool hot = tn < KHOT;
  const int R = hot ? RHOT : RCOLD;
  const float* urow = hot ? (Uh + (size_t)tn * RHOT) : (Uc + (size_t)(tn - KHOT) * RCOLD);
  for (int r = threadIdx.x; r < R; r += blockDim.x) u[r] = urow[r];
  __syncthreads();
  const int gbase = hot ? 0 : RHOT;
  for (int c = threadIdx.x; c < RF; c += blockDim.x) {
    float acc = 0.f;
    for (int r = 0; r < R; ++r) acc += u[r] * G[(size_t)(gbase + r) * RF + c];
    F[(size_t)n * RF + c] = __float2bfloat16(acc);
  }
}

// ---------------- K3 v3: block tile 64 rows x 256 cols, LDS-transposed epilogue ----------------
// 4 waves; wave w owns cols [bx*256 + w*64, +64) as 4 MFMA col-subtiles x 4 row-tiles in regs.
// Epilogue: per 16-row chunk, stage scaled results in LDS, then each wave stores whole rows
// as 1KB-contiguous dwordx4 runs (64 lanes x 16B) -> no partial cache lines.
#define CPB 256
#define RPB 64

__global__ __launch_bounds__(256) void k_out(const int* __restrict__ o2n,
                                             const __hip_bfloat16* __restrict__ F,
                                             const __hip_bfloat16* __restrict__ Uh,
                                             const __hip_bfloat16* __restrict__ Uc,
                                             const float* __restrict__ log_alpha,
                                             const float* __restrict__ bias,
                                             float* __restrict__ out) {
  __shared__ __hip_bfloat16 Fc[RPB][40];  // cold F slice [64 rows][32 cols], pitch 40
  __shared__ float Epi[16][260];          // epilogue staging, pitch 260 (1040B, 16B-aligned rows)
  const int tid = threadIdx.x;
  const int wave = tid >> 6;
  const int lane = tid & 63;
  const int col16 = lane & 15;
  const int g4 = lane >> 4;
  const int n0 = blockIdx.y * RPB;
  const int cbase = blockIdx.x * CPB;
  const float alpha = expf(log_alpha[0]);
  const short8 zero8 = (short8){0, 0, 0, 0, 0, 0, 0, 0};

  // stage cold F slice: 64 rows x 32 cols (16B per thread, 256 threads exactly)
  {
    const int row = tid >> 2, chunk = tid & 3;
    short8 v = *reinterpret_cast<const short8*>(F + (size_t)(n0 + row) * RF + RHOT + chunk * 8);
    *reinterpret_cast<short8*>(&Fc[row][chunk * 8]) = v;
  }
  __syncthreads();

  // per-col-subtile metadata
  int src[4];
  float bv[4];
  bool hotcs[4];
#pragma unroll
  for (int cs = 0; cs < 4; ++cs) {
    const int v = cbase + wave * 64 + cs * 16 + col16;
    const int vc = (v < VOUT) ? v : (VOUT - 1);
    src[cs] = o2n[vc];
    bv[cs] = bias[vc];
    hotcs[cs] = __any(src[cs] < KHOT);
  }

  f32x4 acc[4][4];  // [cs][t]
#pragma unroll
  for (int cs = 0; cs < 4; ++cs)
#pragma unroll
    for (int t = 0; t < 4; ++t) acc[cs][t] = (f32x4){0.f, 0.f, 0.f, 0.f};

  // cold contribution: K = 32 from LDS (afrag shared across cs)
  {
    short8 afc[4];
#pragma unroll
    for (int t = 0; t < 4; ++t)
      afc[t] = *reinterpret_cast<const short8*>(&Fc[t * 16 + col16][g4 * 8]);
#pragma unroll
    for (int cs = 0; cs < 4; ++cs) {
      if (__any(src[cs] >= KHOT)) {
        short8 bfrag = zero8;
        if (src[cs] >= KHOT)
          bfrag = *reinterpret_cast<const short8*>(Uc + (size_t)(src[cs] - KHOT) * RCOLD + g4 * 8);
#pragma unroll
        for (int t = 0; t < 4; ++t)
          acc[cs][t] = __builtin_amdgcn_mfma_f32_16x16x32_bf16(afc[t], bfrag, acc[cs][t], 0, 0, 0);
      }
    }
  }
  // hot contribution: K = 384, 12 K-steps (rare: only blocks containing hot columns)
  if (hotcs[0] | hotcs[1] | hotcs[2] | hotcs[3]) {
    for (int ks = 0; ks < RHOT / 32; ++ks) {
      short8 afh[4];
#pragma unroll
      for (int t = 0; t < 4; ++t)
        afh[t] = *reinterpret_cast<const short8*>(
            F + (size_t)(n0 + t * 16 + col16) * RF + ks * 32 + g4 * 8);
#pragma unroll
      for (int cs = 0; cs < 4; ++cs) {
        if (hotcs[cs]) {
          short8 bfrag = zero8;
          if (src[cs] < KHOT)
            bfrag = *reinterpret_cast<const short8*>(Uh + (size_t)src[cs] * RHOT + ks * 32 + g4 * 8);
#pragma unroll
          for (int t = 0; t < 4; ++t)
            acc[cs][t] = __builtin_amdgcn_mfma_f32_16x16x32_bf16(afh[t], bfrag, acc[cs][t], 0, 0, 0);
        }
      }
    }
  }

  // epilogue: 4 chunks of 16 rows; LDS transpose -> 1KB contiguous stores per instruction
  for (int t = 0; t < 4; ++t) {
    __syncthreads();  // previous chunk's stores done before overwrite
#pragma unroll
    for (int cs = 0; cs < 4; ++cs) {
#pragma unroll
      for (int r = 0; r < 4; ++r)
        Epi[g4 * 4 + r][wave * 64 + cs * 16 + col16] = acc[cs][t][r] * alpha + bv[cs];
    }
    __syncthreads();
#pragma unroll
    for (int rr = 0; rr < 4; ++rr) {
      const int row = wave * 4 + rr;
      f32x4 vals = *reinterpret_cast<const f32x4*>(&Epi[row][lane * 4]);
      const size_t gr = (size_t)(n0 + t * 16 + row) * VOUT;
      const int c0 = cbase + lane * 4;
      if (c0 + 3 < VOUT) {
        *reinterpret_cast<f32x4*>(out + gr + c0) = vals;
      } else {
#pragma unroll
        for (int j = 0; j < 4; ++j)
          if (c0 + j < VOUT) out[gr + c0 + j] = vals[j];
      }
    }
  }
}

extern "C" void kernel_launch(void* const* d_in, const int* in_sizes, int n_in,
                              void* d_out, int out_size, void* d_ws, size_t ws_size,
                              hipStream_t stream) {
  const int* tokens    = (const int*)d_in[0];
  const int* o2n       = (const int*)d_in[1];
  const float* B_hot   = (const float*)d_in[2];
  const float* B_cold  = (const float*)d_in[3];
  const float* U_hot   = (const float*)d_in[4];
  const float* U_cold  = (const float*)d_in[5];
  const float* log_a   = (const float*)d_in[6];
  const float* bias    = (const float*)d_in[7];
  float* out = (float*)d_out;

  const int N = in_sizes[0];  // 4096 tokens

  // workspace layout (bytes)
  char* ws = (char*)d_ws;
  __hip_bfloat16* Bmat = (__hip_bfloat16*)(ws + 0);             // 425984*2
  __hip_bfloat16* UhB  = (__hip_bfloat16*)(ws + (1u << 20));    // 393216*2
  __hip_bfloat16* UcB  = (__hip_bfloat16*)(ws + (2u << 20));    // 1575456*2
  float*          G    = (float*)(ws + (6u << 20));             // 416*416*4
  __hip_bfloat16* F    = (__hip_bfloat16*)(ws + (7u << 20));    // 4096*416*2

  k_convert<<<2048, 256, 0, stream>>>(B_hot, B_cold, U_hot, U_cold, Bmat, UhB, UcB);
  k_gram<<<169, 256, 0, stream>>>(Bmat, G);
  k_encode<<<N, 256, 0, stream>>>(tokens, o2n, U_hot, U_cold, G, F);

  dim3 grid((VOUT + CPB - 1) / CPB, N / RPB);
  k_out<<<grid, 256, 0, stream>>>(o2n, F, UhB, UcB, log_a, bias, out);
}